// Round 5
// baseline (358.035 us; speedup 1.0000x reference)
//
#include <hip/hip_runtime.h>

#define EPS 1e-5f

typedef short short8 __attribute__((ext_vector_type(8)));
typedef float floatx4 __attribute__((ext_vector_type(4)));
typedef unsigned short ushort8 __attribute__((ext_vector_type(8)));

__device__ __forceinline__ unsigned short f2bf(float f) {
  unsigned int u = __float_as_uint(f);
  u = (u + 0x7FFFu + ((u >> 16) & 1u)) >> 16;
  return (unsigned short)u;
}

// 4-byte-aligned 4-float load (gfx9+ supports dword-aligned dwordx4)
struct __attribute__((aligned(4))) F4 {
  float v[4];
};
__device__ __forceinline__ F4 ldg4(const float* p) { return *reinterpret_cast<const F4*>(p); }

// ---------------------------------------------------------------------------
// Kernel 1: qkv[b][o][h] = BN(qkv_w @ x)  via bf16 MFMA 16x16x32. (unchanged)
// ---------------------------------------------------------------------------
__global__ __launch_bounds__(256) void k_qkv_gemm(const float* __restrict__ x,
                                                  const float* __restrict__ W,
                                                  const float* __restrict__ bnq,
                                                  float* __restrict__ qkv) {
  __shared__ unsigned short A_lds[64 * 72];  // [m][k]
  __shared__ unsigned short B_lds[64 * 66];  // [k][n]
  const int tid = threadIdx.x;
  const int lane = tid & 63;
  const int wid = tid >> 6;
  const int wm = (wid >> 1) * 32, wn = (wid & 1) * 32;
  const int n0 = blockIdx.x * 64;
  const int o0 = blockIdx.y * 64;
  const int l15 = lane & 15, kg = lane >> 4;

  floatx4 acc[2][2] = {};

  const int am = tid >> 2, akq = (tid & 3) * 16;
  const int bk = tid >> 2, bnq4 = (tid & 3) * 16;

  for (int ko = 0; ko < 256; ko += 64) {
    __syncthreads();
    {
      unsigned short tmp[16];
#pragma unroll
      for (int u = 0; u < 4; ++u) {
        const float4 w4 =
            *reinterpret_cast<const float4*>(&W[(size_t)(o0 + am) * 256 + ko + akq + u * 4]);
        tmp[u * 4 + 0] = f2bf(w4.x);
        tmp[u * 4 + 1] = f2bf(w4.y);
        tmp[u * 4 + 2] = f2bf(w4.z);
        tmp[u * 4 + 3] = f2bf(w4.w);
      }
      *reinterpret_cast<ushort8*>(&A_lds[am * 72 + akq]) = *reinterpret_cast<ushort8*>(&tmp[0]);
      *reinterpret_cast<ushort8*>(&A_lds[am * 72 + akq + 8]) =
          *reinterpret_cast<ushort8*>(&tmp[8]);
    }
    {
#pragma unroll
      for (int u = 0; u < 4; ++u) {
        const float4 x4 =
            *reinterpret_cast<const float4*>(&x[(size_t)(ko + bk) * 32768 + n0 + bnq4 + u * 4]);
        unsigned int p0 = (unsigned int)f2bf(x4.x) | ((unsigned int)f2bf(x4.y) << 16);
        unsigned int p1 = (unsigned int)f2bf(x4.z) | ((unsigned int)f2bf(x4.w) << 16);
        *reinterpret_cast<unsigned int*>(&B_lds[bk * 66 + bnq4 + u * 4]) = p0;
        *reinterpret_cast<unsigned int*>(&B_lds[bk * 66 + bnq4 + u * 4 + 2]) = p1;
      }
    }
    __syncthreads();
#pragma unroll
    for (int kk = 0; kk < 64; kk += 32) {
      short8 afr[2], bfr[2];
#pragma unroll
      for (int fm = 0; fm < 2; ++fm) {
        const int mrow = wm + fm * 16 + l15;
        afr[fm] = *reinterpret_cast<const short8*>(&A_lds[mrow * 72 + kk + kg * 8]);
      }
#pragma unroll
      for (int fn = 0; fn < 2; ++fn) {
        const int ncol = wn + fn * 16 + l15;
        short8 bv;
#pragma unroll
        for (int e = 0; e < 8; ++e) bv[e] = (short)B_lds[(kk + kg * 8 + e) * 66 + ncol];
        bfr[fn] = bv;
      }
#pragma unroll
      for (int fm = 0; fm < 2; ++fm)
#pragma unroll
        for (int fn = 0; fn < 2; ++fn)
          acc[fm][fn] =
              __builtin_amdgcn_mfma_f32_16x16x32_bf16(afr[fm], bfr[fn], acc[fm][fn], 0, 0, 0);
    }
  }

  const int b = blockIdx.x;
#pragma unroll
  for (int fm = 0; fm < 2; ++fm) {
    float sc[4], sh[4];
#pragma unroll
    for (int reg = 0; reg < 4; ++reg) {
      const int o = o0 + wm + fm * 16 + kg * 4 + reg;
      sc[reg] = bnq[o] / sqrtf(bnq[1536 + o] + EPS);
      sh[reg] = bnq[512 + o] - bnq[1024 + o] * sc[reg];
    }
#pragma unroll
    for (int fn = 0; fn < 2; ++fn) {
      const int h = wn + fn * 16 + l15;
#pragma unroll
      for (int reg = 0; reg < 4; ++reg) {
        const int o = o0 + wm + fm * 16 + kg * 4 + reg;
        qkv[((size_t)b * 512 + o) * 64 + h] = fmaf(acc[fm][fn][reg], sc[reg], sh[reg]);
      }
    }
  }
}

// ---------------------------------------------------------------------------
// Kernel 2: per (b,g) attention, fp32, vectorized, rel read from global.
// LDS: qk_s [32][68] fp32 (8.7KB) + vT_s [64][33] (8.4KB) + S_s [64][68]
// (17.4KB) + rowsum = ~35KB -> 4 blocks/CU.
// ---------------------------------------------------------------------------
__global__ __launch_bounds__(256) void k_attn(const float* __restrict__ qkv,
                                              const float* __restrict__ rel,
                                              const float* __restrict__ bns,
                                              const float* __restrict__ bno,
                                              float* __restrict__ out) {
  __shared__ float qk_s[32 * 68];   // q rows 0..15, k rows 16..31; [cc][h]
  __shared__ float vT_s[64 * 33];   // v transposed: [h][c], stride 33
  __shared__ float S_s[64 * 68];    // scores / P / out-tile
  __shared__ float rowsum_s[64];
  const int tid = threadIdx.x;
  const int bg = blockIdx.x;
  const int b = bg >> 3, g = bg & 7;

  // --- stage qkv block: rows <32 -> qk_s, rows >=32 transposed -> vT_s ---
  {
    const float* src = qkv + ((size_t)b * 512 + (size_t)g * 64) * 64;
    const int cc = tid >> 2, h0 = (tid & 3) * 16;
    const float* s = src + cc * 64 + h0;
    float4 t0 = *reinterpret_cast<const float4*>(s);
    float4 t1 = *reinterpret_cast<const float4*>(s + 4);
    float4 t2 = *reinterpret_cast<const float4*>(s + 8);
    float4 t3 = *reinterpret_cast<const float4*>(s + 12);
    if (cc < 32) {
      float* dst = qk_s + cc * 68 + h0;
      *reinterpret_cast<float4*>(dst) = t0;
      *reinterpret_cast<float4*>(dst + 4) = t1;
      *reinterpret_cast<float4*>(dst + 8) = t2;
      *reinterpret_cast<float4*>(dst + 12) = t3;
    } else {
      const int c = cc - 32;
      const float tmp[16] = {t0.x, t0.y, t0.z, t0.w, t1.x, t1.y, t1.z, t1.w,
                             t2.x, t2.y, t2.z, t2.w, t3.x, t3.y, t3.z, t3.w};
#pragma unroll
      for (int e = 0; e < 16; ++e) vT_s[(h0 + e) * 33 + c] = tmp[e];
    }
  }
  __syncthreads();

  // --- step 2: scores. thread = (j = tid&63, i-block of 16 = (tid>>6)*16) ---
  {
    const int j = tid & 63;
    const int i0 = (tid >> 6) * 16;
    float kcol[16];
#pragma unroll
    for (int c = 0; c < 16; ++c) kcol[c] = qk_s[(16 + c) * 68 + j];
    const float scA = bns[g] / sqrtf(bns[72 + g] + EPS);
    const float scB = bns[8 + g] / sqrtf(bns[72 + 8 + g] + EPS);
    const float scC = bns[16 + g] / sqrtf(bns[72 + 16 + g] + EPS);
    const float sh = (bns[24 + g] - bns[48 + g] * scA) +
                     (bns[24 + 8 + g] - bns[48 + 8 + g] * scB) +
                     (bns[24 + 16 + g] - bns[48 + 16 + g] * scC);
#pragma unroll
    for (int ch = 0; ch < 16; ch += 4) {
      const int ib = i0 + ch;
      float qkA[4] = {0.f, 0.f, 0.f, 0.f};
      float qrA[4] = {0.f, 0.f, 0.f, 0.f};
      float krA[4] = {0.f, 0.f, 0.f, 0.f};
#pragma unroll
      for (int c = 0; c < 16; ++c) {
        const float4 q4 = *reinterpret_cast<const float4*>(&qk_s[c * 68 + ib]);  // broadcast
        const F4 rq = ldg4(rel + c * 127 + ib - j + 63);            // elem d <-> i=ib+d
        const F4 rk = ldg4(rel + (16 + c) * 127 + j - ib + 60);     // elem 3-d <-> i=ib+d
        const float qe[4] = {q4.x, q4.y, q4.z, q4.w};
#pragma unroll
        for (int d = 0; d < 4; ++d) {
          qkA[d] = fmaf(qe[d], kcol[c], qkA[d]);
          qrA[d] = fmaf(qe[d], rq.v[d], qrA[d]);
          krA[d] = fmaf(kcol[c], rk.v[3 - d], krA[d]);
        }
      }
#pragma unroll
      for (int d = 0; d < 4; ++d)
        S_s[(ib + d) * 68 + j] = fmaf(scA, qkA[d], fmaf(scB, qrA[d], fmaf(scC, krA[d], sh)));
    }
  }
  __syncthreads();

  // --- step 3: softmax over j (4 threads per row, float4, shuffle reduce) ---
  {
    const int i = tid >> 2, sub = tid & 3;
    float* row = S_s + i * 68 + sub * 16;
    float4 v0 = reinterpret_cast<float4*>(row)[0];
    float4 v1 = reinterpret_cast<float4*>(row)[1];
    float4 v2 = reinterpret_cast<float4*>(row)[2];
    float4 v3 = reinterpret_cast<float4*>(row)[3];
    float m = fmaxf(fmaxf(fmaxf(v0.x, v0.y), fmaxf(v0.z, v0.w)),
                    fmaxf(fmaxf(v1.x, v1.y), fmaxf(v1.z, v1.w)));
    m = fmaxf(m, fmaxf(fmaxf(fmaxf(v2.x, v2.y), fmaxf(v2.z, v2.w)),
                       fmaxf(fmaxf(v3.x, v3.y), fmaxf(v3.z, v3.w))));
    m = fmaxf(m, __shfl_xor(m, 1));
    m = fmaxf(m, __shfl_xor(m, 2));
    float4 e0, e1, e2, e3;
    e0.x = __expf(v0.x - m); e0.y = __expf(v0.y - m); e0.z = __expf(v0.z - m); e0.w = __expf(v0.w - m);
    e1.x = __expf(v1.x - m); e1.y = __expf(v1.y - m); e1.z = __expf(v1.z - m); e1.w = __expf(v1.w - m);
    e2.x = __expf(v2.x - m); e2.y = __expf(v2.y - m); e2.z = __expf(v2.z - m); e2.w = __expf(v2.w - m);
    e3.x = __expf(v3.x - m); e3.y = __expf(v3.y - m); e3.z = __expf(v3.z - m); e3.w = __expf(v3.w - m);
    float sum = e0.x + e0.y + e0.z + e0.w + e1.x + e1.y + e1.z + e1.w +
                e2.x + e2.y + e2.z + e2.w + e3.x + e3.y + e3.z + e3.w;
    reinterpret_cast<float4*>(row)[0] = e0;
    reinterpret_cast<float4*>(row)[1] = e1;
    reinterpret_cast<float4*>(row)[2] = e2;
    reinterpret_cast<float4*>(row)[3] = e3;
    sum += __shfl_xor(sum, 1);
    sum += __shfl_xor(sum, 2);
    if (sub == 0) rowsum_s[i] = sum;
  }
  __syncthreads();

  // --- step 4: sv/sve + output BN. thread c = tid&31; i = (tid>>5) + 8r ---
  const int c = tid & 31;
  float vrow[64];
#pragma unroll
  for (int jj = 0; jj < 64; ++jj) vrow[jj] = vT_s[jj * 33 + c];  // stride-1 banks
  const float* relc = rel + (32 + c) * 127;
  const int chn = ((g << 5) + c) * 2;
  const float sc0 = bno[chn] / sqrtf(bno[1536 + chn] + EPS);
  const float sh0 = bno[512 + chn] - bno[1024 + chn] * sc0;
  const float sc1 = bno[chn + 1] / sqrtf(bno[1536 + chn + 1] + EPS);
  const float sh1 = bno[512 + chn + 1] - bno[1024 + chn + 1] * sc1;
  float outv[8];
#pragma unroll
  for (int r = 0; r < 8; ++r) {
    const int i = (tid >> 5) + 8 * r;
    const float* prow = S_s + i * 68;
    const int rbase = i + 63;
    float sv = 0.f, sve = 0.f;
#pragma unroll
    for (int jj4 = 0; jj4 < 16; ++jj4) {
      const float4 p4 = *reinterpret_cast<const float4*>(prow + jj4 * 4);
      const F4 rv = ldg4(relc + rbase - jj4 * 4 - 3);  // rv.v[3-e] <-> jj4*4+e
      const float pe[4] = {p4.x, p4.y, p4.z, p4.w};
#pragma unroll
      for (int e = 0; e < 4; ++e) {
        sv = fmaf(pe[e], vrow[jj4 * 4 + e], sv);
        sve = fmaf(pe[e], rv.v[3 - e], sve);
      }
    }
    const float inv = 1.0f / rowsum_s[i];
    outv[r] = fmaf(sc0, sv * inv, sh0) + fmaf(sc1, sve * inv, sh1);
  }
  __syncthreads();  // everyone done reading S_s as P
#pragma unroll
  for (int r = 0; r < 8; ++r) {
    const int i = (tid >> 5) + 8 * r;
    S_s[c * 68 + i] = outv[r];  // out-tile [c][i]
  }
  __syncthreads();
  const size_t outbase = (size_t)b * 64;
  for (int idx = tid; idx < 2048; idx += 256) {
    const int cc = idx >> 6, ii = idx & 63;
    out[(size_t)((g << 5) + cc) * 32768 + outbase + ii] = S_s[cc * 68 + ii];
  }
}

extern "C" void kernel_launch(void* const* d_in, const int* in_sizes, int n_in,
                              void* d_out, int out_size, void* d_ws, size_t ws_size,
                              hipStream_t stream) {
  const float* x = (const float*)d_in[0];         // (1,256,16,32,64)
  const float* qkv_w = (const float*)d_in[1];     // (512,256)
  const float* relative = (const float*)d_in[2];  // (64,127)
  const float* bn_qkv = (const float*)d_in[3];    // (4,512)
  const float* bn_sim = (const float*)d_in[4];    // (4,24)
  const float* bn_out = (const float*)d_in[5];    // (4,512)
  float* out = (float*)d_out;                     // (256, 512, 64) as [op][b][h]
  float* qkv = (float*)d_ws;                      // 64 MB scratch

  k_qkv_gemm<<<dim3(512, 8), 256, 0, stream>>>(x, qkv_w, bn_qkv, qkv);
  k_attn<<<4096, 256, 0, stream>>>(qkv, relative, bn_sim, bn_out, out);
}

// Round 6
// 162.604 us; speedup vs baseline: 2.2019x; 2.2019x over previous
//
#include <hip/hip_runtime.h>

#define EPS 1e-5f

typedef short short8 __attribute__((ext_vector_type(8)));
typedef float floatx4 __attribute__((ext_vector_type(4)));
typedef unsigned short ushort8 __attribute__((ext_vector_type(8)));

__device__ __forceinline__ unsigned short f2bf(float f) {
  unsigned int u = __float_as_uint(f);
  u = (u + 0x7FFFu + ((u >> 16) & 1u)) >> 16;
  return (unsigned short)u;
}
__device__ __forceinline__ float bf2f(unsigned short h) {
  return __uint_as_float(((unsigned int)h) << 16);
}

// ---------------------------------------------------------------------------
// Kernel 1: qkv = BN(W @ x), split-bf16 (hi/lo) MFMA => ~fp32 accuracy.
// C = Wh*xh + Wh*xl + Wl*xh  (3 MFMAs per tile-k)
// ---------------------------------------------------------------------------
__global__ __launch_bounds__(256) void k_qkv_gemm(const float* __restrict__ x,
                                                  const float* __restrict__ W,
                                                  const float* __restrict__ bnq,
                                                  float* __restrict__ qkv) {
  __shared__ unsigned short Ah[64 * 72], Al[64 * 72];  // [m][k] stride 72 sh (144B)
  __shared__ unsigned short Bh[64 * 66], Bl[64 * 66];  // [k][n] stride 66 sh
  const int tid = threadIdx.x;
  const int lane = tid & 63;
  const int wid = tid >> 6;
  const int wm = (wid >> 1) * 32, wn = (wid & 1) * 32;
  const int n0 = blockIdx.x * 64;
  const int o0 = blockIdx.y * 64;
  const int l15 = lane & 15, kg = lane >> 4;

  floatx4 acc[2][2] = {};

  const int am = tid >> 2, akq = (tid & 3) * 16;
  const int bk = tid >> 2, bn4 = (tid & 3) * 16;

  for (int ko = 0; ko < 256; ko += 64) {
    __syncthreads();
    {  // stage A (W) hi/lo
      unsigned short th[16], tl[16];
#pragma unroll
      for (int u = 0; u < 4; ++u) {
        const float4 w4 =
            *reinterpret_cast<const float4*>(&W[(size_t)(o0 + am) * 256 + ko + akq + u * 4]);
        const float we[4] = {w4.x, w4.y, w4.z, w4.w};
#pragma unroll
        for (int e = 0; e < 4; ++e) {
          const unsigned short hi = f2bf(we[e]);
          th[u * 4 + e] = hi;
          tl[u * 4 + e] = f2bf(we[e] - bf2f(hi));
        }
      }
      *reinterpret_cast<ushort8*>(&Ah[am * 72 + akq]) = *reinterpret_cast<ushort8*>(&th[0]);
      *reinterpret_cast<ushort8*>(&Ah[am * 72 + akq + 8]) = *reinterpret_cast<ushort8*>(&th[8]);
      *reinterpret_cast<ushort8*>(&Al[am * 72 + akq]) = *reinterpret_cast<ushort8*>(&tl[0]);
      *reinterpret_cast<ushort8*>(&Al[am * 72 + akq + 8]) = *reinterpret_cast<ushort8*>(&tl[8]);
    }
    {  // stage B (x) hi/lo
#pragma unroll
      for (int u = 0; u < 4; ++u) {
        const float4 x4 =
            *reinterpret_cast<const float4*>(&x[(size_t)(ko + bk) * 32768 + n0 + bn4 + u * 4]);
        const float xe[4] = {x4.x, x4.y, x4.z, x4.w};
        unsigned short h[4], l[4];
#pragma unroll
        for (int e = 0; e < 4; ++e) {
          h[e] = f2bf(xe[e]);
          l[e] = f2bf(xe[e] - bf2f(h[e]));
        }
        unsigned int* dh = reinterpret_cast<unsigned int*>(&Bh[bk * 66 + bn4 + u * 4]);
        unsigned int* dl = reinterpret_cast<unsigned int*>(&Bl[bk * 66 + bn4 + u * 4]);
        dh[0] = (unsigned int)h[0] | ((unsigned int)h[1] << 16);
        dh[1] = (unsigned int)h[2] | ((unsigned int)h[3] << 16);
        dl[0] = (unsigned int)l[0] | ((unsigned int)l[1] << 16);
        dl[1] = (unsigned int)l[2] | ((unsigned int)l[3] << 16);
      }
    }
    __syncthreads();
#pragma unroll
    for (int kk = 0; kk < 64; kk += 32) {
      short8 ah[2], al2[2];
#pragma unroll
      for (int fm = 0; fm < 2; ++fm) {
        const int mrow = wm + fm * 16 + l15;
        ah[fm] = *reinterpret_cast<const short8*>(&Ah[mrow * 72 + kk + kg * 8]);
        al2[fm] = *reinterpret_cast<const short8*>(&Al[mrow * 72 + kk + kg * 8]);
      }
      short8 bh[2], bl2[2];
#pragma unroll
      for (int fn = 0; fn < 2; ++fn) {
        const int ncol = wn + fn * 16 + l15;
        short8 bvh, bvl;
#pragma unroll
        for (int e = 0; e < 8; ++e) {
          bvh[e] = (short)Bh[(kk + kg * 8 + e) * 66 + ncol];
          bvl[e] = (short)Bl[(kk + kg * 8 + e) * 66 + ncol];
        }
        bh[fn] = bvh;
        bl2[fn] = bvl;
      }
#pragma unroll
      for (int fm = 0; fm < 2; ++fm)
#pragma unroll
        for (int fn = 0; fn < 2; ++fn) {
          acc[fm][fn] =
              __builtin_amdgcn_mfma_f32_16x16x32_bf16(ah[fm], bh[fn], acc[fm][fn], 0, 0, 0);
          acc[fm][fn] =
              __builtin_amdgcn_mfma_f32_16x16x32_bf16(ah[fm], bl2[fn], acc[fm][fn], 0, 0, 0);
          acc[fm][fn] =
              __builtin_amdgcn_mfma_f32_16x16x32_bf16(al2[fm], bh[fn], acc[fm][fn], 0, 0, 0);
        }
    }
  }

  const int b = blockIdx.x;
#pragma unroll
  for (int fm = 0; fm < 2; ++fm) {
    float sc[4], sh[4];
#pragma unroll
    for (int reg = 0; reg < 4; ++reg) {
      const int o = o0 + wm + fm * 16 + kg * 4 + reg;
      sc[reg] = bnq[o] / sqrtf(bnq[1536 + o] + EPS);
      sh[reg] = bnq[512 + o] - bnq[1024 + o] * sc[reg];
    }
#pragma unroll
    for (int fn = 0; fn < 2; ++fn) {
      const int h = wn + fn * 16 + l15;
#pragma unroll
      for (int reg = 0; reg < 4; ++reg) {
        const int o = o0 + wm + fm * 16 + kg * 4 + reg;
        qkv[((size_t)b * 512 + o) * 64 + h] = fmaf(acc[fm][fn][reg], sc[reg], sh[reg]);
      }
    }
  }
}

// ---------------------------------------------------------------------------
// Kernel 2: per (b,g) attention via MFMA.
//  qk = q^T k (in regs); M1 = q^T rel_q; M2 = k^T rel_k  (K=16 zero-pad 32)
//  S[i][j] = scA*qk + scB*M1[i][i-j+63] + scC*M2[j][j-i+63] + sh
//  softmax -> P (bf16) and P'[i][t]=P[i][i+63-t] (scatter, zero-filled)
//  sv = P v^T (K=64); sve = P' rel_v^T (K=128); out = bn0(sv/l) + bn1(sve/l)
// LDS arena 80896B, phase-overlaid; 2 blocks/CU.
// ---------------------------------------------------------------------------
#define SK 40    // staging row stride (shorts): qT,kT,rq,rk
#define M1S 130  // M1/M2 row stride (shorts)
#define PS 72    // P row stride (shorts)
#define PPS 136  // P' / RV row stride (shorts)
#define SS 66    // S row stride (floats); col 64 = rowsum

__global__ __launch_bounds__(256) void k_attn(const float* __restrict__ qkv,
                                              const float* __restrict__ rel,
                                              const float* __restrict__ bns,
                                              const float* __restrict__ bno,
                                              float* __restrict__ out) {
  __shared__ __align__(16) char arena[80896];
  float* S_s = reinterpret_cast<float*>(arena);                          // 16896
  unsigned short* qT = reinterpret_cast<unsigned short*>(arena + 16896); // 5120
  unsigned short* kT = reinterpret_cast<unsigned short*>(arena + 22016); // 5120
  unsigned short* rq = reinterpret_cast<unsigned short*>(arena + 27136); // 10240
  unsigned short* rk = reinterpret_cast<unsigned short*>(arena + 37376); // 10240
  unsigned short* Pp = reinterpret_cast<unsigned short*>(arena + 16896); // 17408 (overlay)
  unsigned short* Pb = reinterpret_cast<unsigned short*>(arena + 34304); // 9216  (overlay)
  unsigned short* M1 = reinterpret_cast<unsigned short*>(arena + 47616); // 16640
  unsigned short* M2 = reinterpret_cast<unsigned short*>(arena + 64256); // 16640
  unsigned short* Vb = reinterpret_cast<unsigned short*>(arena + 47616); // 4608  (overlay)
  unsigned short* RVb = reinterpret_cast<unsigned short*>(arena + 52224);// 8704  (overlay)

  const int tid = threadIdx.x;
  const int lane = tid & 63;
  const int wid = tid >> 6;
  const int l15 = lane & 15, kg = lane >> 4;
  const int bg = blockIdx.x;
  const int b = bg >> 3, g = bg & 7;
  const float* src = qkv + ((size_t)b * 512 + (size_t)g * 64) * 64;

  const float scA = bns[g] / sqrtf(bns[72 + g] + EPS);
  const float scB = bns[8 + g] / sqrtf(bns[72 + 8 + g] + EPS);
  const float scC = bns[16 + g] / sqrtf(bns[72 + 16 + g] + EPS);
  const float shv = (bns[24 + g] - bns[48 + g] * scA) +
                    (bns[24 + 8 + g] - bns[48 + 8 + g] * scB) +
                    (bns[24 + 16 + g] - bns[48 + 16 + g] * scC);

  // ---- phase 1: stage q,k (transposed, k-padded) and rel_q, rel_k ----
  {
    const int c = tid >> 4, i0 = (tid & 15) * 4;
    const float4 qv = *reinterpret_cast<const float4*>(&src[c * 64 + i0]);
    const float4 kv = *reinterpret_cast<const float4*>(&src[(16 + c) * 64 + i0]);
    const float qe[4] = {qv.x, qv.y, qv.z, qv.w};
    const float ke[4] = {kv.x, kv.y, kv.z, kv.w};
#pragma unroll
    for (int e = 0; e < 4; ++e) {
      qT[(i0 + e) * SK + c] = f2bf(qe[e]);
      qT[(i0 + e) * SK + 16 + c] = 0;
      kT[(i0 + e) * SK + c] = f2bf(ke[e]);
      kT[(i0 + e) * SK + 16 + c] = 0;
    }
    const int t0 = (tid & 15) * 8;
#pragma unroll
    for (int e = 0; e < 8; ++e) {
      const int t = t0 + e;
      const unsigned short hq = (t < 127) ? f2bf(rel[c * 127 + t]) : (unsigned short)0;
      const unsigned short hk = (t < 127) ? f2bf(rel[(16 + c) * 127 + t]) : (unsigned short)0;
      rq[t * SK + c] = hq;
      rq[t * SK + 16 + c] = 0;
      rk[t * SK + c] = hk;
      rk[t * SK + 16 + c] = 0;
    }
  }
  __syncthreads();

  // ---- phase 2: GEMMs (wave wid owns m-strip wid) ----
  floatx4 qkreg[4];
  {
    const short8 aq = *reinterpret_cast<const short8*>(&qT[(wid * 16 + l15) * SK + kg * 8]);
#pragma unroll
    for (int nt = 0; nt < 4; ++nt) {
      const short8 bf = *reinterpret_cast<const short8*>(&kT[(nt * 16 + l15) * SK + kg * 8]);
      const floatx4 z = {};
      qkreg[nt] = __builtin_amdgcn_mfma_f32_16x16x32_bf16(aq, bf, z, 0, 0, 0);
    }
#pragma unroll
    for (int nt = 0; nt < 8; ++nt) {
      const short8 bf = *reinterpret_cast<const short8*>(&rq[(nt * 16 + l15) * SK + kg * 8]);
      const floatx4 z = {};
      const floatx4 cr = __builtin_amdgcn_mfma_f32_16x16x32_bf16(aq, bf, z, 0, 0, 0);
#pragma unroll
      for (int r = 0; r < 4; ++r)
        M1[(wid * 16 + kg * 4 + r) * M1S + nt * 16 + l15] = f2bf(cr[r]);
    }
    const short8 ak = *reinterpret_cast<const short8*>(&kT[(wid * 16 + l15) * SK + kg * 8]);
#pragma unroll
    for (int nt = 0; nt < 8; ++nt) {
      const short8 bf = *reinterpret_cast<const short8*>(&rk[(nt * 16 + l15) * SK + kg * 8]);
      const floatx4 z = {};
      const floatx4 cr = __builtin_amdgcn_mfma_f32_16x16x32_bf16(ak, bf, z, 0, 0, 0);
#pragma unroll
      for (int r = 0; r < 4; ++r)
        M2[(wid * 16 + kg * 4 + r) * M1S + nt * 16 + l15] = f2bf(cr[r]);
    }
  }
  __syncthreads();

  // ---- phase 3: zero P' (overlay now dead) + assemble S ----
  {
    unsigned int* pz = reinterpret_cast<unsigned int*>(Pp);
#pragma unroll
    for (int it = 0; it < 17; ++it) pz[tid + it * 256] = 0u;
  }
#pragma unroll
  for (int nt = 0; nt < 4; ++nt) {
    const int j = nt * 16 + l15;
#pragma unroll
    for (int r = 0; r < 4; ++r) {
      const int i = wid * 16 + kg * 4 + r;
      const int d = i - j + 63;  // 0..126
      const float qr = bf2f(M1[i * M1S + d]);
      const float kr = bf2f(M2[j * M1S + 126 - d]);
      S_s[i * SS + j] = fmaf(scA, qkreg[nt][r], fmaf(scB, qr, fmaf(scC, kr, shv)));
    }
  }
  __syncthreads();

  // ---- phase 4: softmax (write P, scatter P') + stage v, rel_v ----
  {
    const int i = tid >> 2, sub = tid & 3;
    const float* row = S_s + i * SS + sub * 16;
    float ev[16];
#pragma unroll
    for (int p = 0; p < 8; ++p) {
      const float2 v2 = *reinterpret_cast<const float2*>(row + p * 2);
      ev[p * 2] = v2.x;
      ev[p * 2 + 1] = v2.y;
    }
    float m = ev[0];
#pragma unroll
    for (int jj = 1; jj < 16; ++jj) m = fmaxf(m, ev[jj]);
    m = fmaxf(m, __shfl_xor(m, 1));
    m = fmaxf(m, __shfl_xor(m, 2));
    float sum = 0.f;
#pragma unroll
    for (int jj = 0; jj < 16; ++jj) {
      ev[jj] = __expf(ev[jj] - m);
      sum += ev[jj];
    }
    sum += __shfl_xor(sum, 1);
    sum += __shfl_xor(sum, 2);
    if (sub == 0) S_s[i * SS + 64] = sum;  // rowsum slot
    unsigned int* pw = reinterpret_cast<unsigned int*>(Pb) + i * (PS / 2) + sub * 8;
#pragma unroll
    for (int p = 0; p < 8; ++p)
      pw[p] = (unsigned int)f2bf(ev[2 * p]) | ((unsigned int)f2bf(ev[2 * p + 1]) << 16);
#pragma unroll
    for (int jj = 0; jj < 16; ++jj) {
      const int t = i + 63 - (sub * 16 + jj);
      Pp[i * PPS + t] = f2bf(ev[jj]);
    }
  }
  {
    const int cv = tid >> 3, j0 = (tid & 7) * 8;
    const float4 a = *reinterpret_cast<const float4*>(&src[(32 + cv) * 64 + j0]);
    const float4 bq = *reinterpret_cast<const float4*>(&src[(32 + cv) * 64 + j0 + 4]);
    unsigned int* dst = reinterpret_cast<unsigned int*>(Vb) + (cv * PS + j0) / 2;
    dst[0] = (unsigned int)f2bf(a.x) | ((unsigned int)f2bf(a.y) << 16);
    dst[1] = (unsigned int)f2bf(a.z) | ((unsigned int)f2bf(a.w) << 16);
    dst[2] = (unsigned int)f2bf(bq.x) | ((unsigned int)f2bf(bq.y) << 16);
    dst[3] = (unsigned int)f2bf(bq.z) | ((unsigned int)f2bf(bq.w) << 16);
    const int t0 = (tid & 7) * 16;
#pragma unroll
    for (int e = 0; e < 16; ++e) {
      const int t = t0 + e;
      RVb[cv * PPS + t] = (t < 127) ? f2bf(rel[(32 + cv) * 127 + t]) : (unsigned short)0;
    }
  }
  __syncthreads();

  // ---- phase 5: sv / sve MFMAs + BN epilogue ----
  floatx4 sva[2] = {}, svea[2] = {};
#pragma unroll
  for (int kk = 0; kk < 2; ++kk) {
    const short8 pa =
        *reinterpret_cast<const short8*>(&Pb[(wid * 16 + l15) * PS + kk * 32 + kg * 8]);
#pragma unroll
    for (int nt = 0; nt < 2; ++nt) {
      const short8 vb =
          *reinterpret_cast<const short8*>(&Vb[(nt * 16 + l15) * PS + kk * 32 + kg * 8]);
      sva[nt] = __builtin_amdgcn_mfma_f32_16x16x32_bf16(pa, vb, sva[nt], 0, 0, 0);
    }
  }
#pragma unroll
  for (int kk = 0; kk < 4; ++kk) {
    const short8 pp =
        *reinterpret_cast<const short8*>(&Pp[(wid * 16 + l15) * PPS + kk * 32 + kg * 8]);
#pragma unroll
    for (int nt = 0; nt < 2; ++nt) {
      const short8 rb =
          *reinterpret_cast<const short8*>(&RVb[(nt * 16 + l15) * PPS + kk * 32 + kg * 8]);
      svea[nt] = __builtin_amdgcn_mfma_f32_16x16x32_bf16(pp, rb, svea[nt], 0, 0, 0);
    }
  }
#pragma unroll
  for (int nt = 0; nt < 2; ++nt) {
    const int c = nt * 16 + l15;
    const int ch = ((g << 5) + c) * 2;
    const float sc0 = bno[ch] / sqrtf(bno[1536 + ch] + EPS);
    const float sh0 = bno[512 + ch] - bno[1024 + ch] * sc0;
    const float sc1 = bno[ch + 1] / sqrtf(bno[1536 + ch + 1] + EPS);
    const float sh1 = bno[512 + ch + 1] - bno[1024 + ch + 1] * sc1;
#pragma unroll
    for (int r = 0; r < 4; ++r) {
      const int i = wid * 16 + kg * 4 + r;
      const float inv = 1.0f / S_s[i * SS + 64];
      const float val = fmaf(sc0, sva[nt][r] * inv, sh0) + fmaf(sc1, svea[nt][r] * inv, sh1);
      S_s[c * SS + i] = val;  // out-tile [c][i]; disjoint from rowsum col 64
    }
  }
  __syncthreads();
  {
    const size_t outbase = (size_t)b * 64;
#pragma unroll
    for (int r = 0; r < 8; ++r) {
      const int idx = tid + r * 256;
      const int cc = idx >> 6, ii = idx & 63;
      out[(size_t)((g << 5) + cc) * 32768 + outbase + ii] = S_s[cc * SS + ii];
    }
  }
}

extern "C" void kernel_launch(void* const* d_in, const int* in_sizes, int n_in,
                              void* d_out, int out_size, void* d_ws, size_t ws_size,
                              hipStream_t stream) {
  const float* x = (const float*)d_in[0];         // (1,256,16,32,64)
  const float* qkv_w = (const float*)d_in[1];     // (512,256)
  const float* relative = (const float*)d_in[2];  // (64,127)
  const float* bn_qkv = (const float*)d_in[3];    // (4,512)
  const float* bn_sim = (const float*)d_in[4];    // (4,24)
  const float* bn_out = (const float*)d_in[5];    // (4,512)
  float* out = (float*)d_out;                     // (256, 512, 64) as [op][b][h]
  float* qkv = (float*)d_ws;                      // 64 MB scratch

  k_qkv_gemm<<<dim3(512, 8), 256, 0, stream>>>(x, qkv_w, bn_qkv, qkv);
  k_attn<<<4096, 256, 0, stream>>>(qkv, relative, bn_sim, bn_out, out);
}

// Round 7
// 143.576 us; speedup vs baseline: 2.4937x; 1.1325x over previous
//
#include <hip/hip_runtime.h>

#define EPS 1e-5f

typedef _Float16 half4_t __attribute__((ext_vector_type(4)));
typedef _Float16 half8_t __attribute__((ext_vector_type(8)));
typedef float floatx4 __attribute__((ext_vector_type(4)));

__device__ __forceinline__ unsigned short f2hb(float f) {
  _Float16 h = (_Float16)f;
  return __builtin_bit_cast(unsigned short, h);
}
__device__ __forceinline__ float hb2f(unsigned short u) {
  return (float)__builtin_bit_cast(_Float16, u);
}
__device__ __forceinline__ unsigned int pack2(float a, float b) {
  return (unsigned int)f2hb(a) | ((unsigned int)f2hb(b) << 16);
}

// ---------------------------------------------------------------------------
// Kernel 1: qkv[b][o][h] = BN(qkv_w @ x), fp16 MFMA 16x16x32, single-pass.
// ---------------------------------------------------------------------------
__global__ __launch_bounds__(256) void k_qkv_gemm(const float* __restrict__ x,
                                                  const float* __restrict__ W,
                                                  const float* __restrict__ bnq,
                                                  float* __restrict__ qkv) {
  __shared__ unsigned short Ah[64 * 72];  // [m][k] stride 72 (144B rows)
  __shared__ unsigned short Bh[64 * 66];  // [k][n] stride 66 (odd dwords)
  const int tid = threadIdx.x;
  const int lane = tid & 63;
  const int wid = tid >> 6;
  const int wm = (wid >> 1) * 32, wn = (wid & 1) * 32;
  const int n0 = blockIdx.x * 64;
  const int o0 = blockIdx.y * 64;
  const int l15 = lane & 15, kg = lane >> 4;

  floatx4 acc[2][2] = {};

  const int am = tid >> 2, akq = (tid & 3) * 16;
  const int bk = tid >> 2, bn4 = (tid & 3) * 16;

  for (int ko = 0; ko < 256; ko += 64) {
    __syncthreads();
    {  // stage A (W) -> fp16
      unsigned int tp[8];
#pragma unroll
      for (int u = 0; u < 4; ++u) {
        const float4 w4 =
            *reinterpret_cast<const float4*>(&W[(size_t)(o0 + am) * 256 + ko + akq + u * 4]);
        tp[u * 2] = pack2(w4.x, w4.y);
        tp[u * 2 + 1] = pack2(w4.z, w4.w);
      }
      uint4 s0 = {tp[0], tp[1], tp[2], tp[3]};
      uint4 s1 = {tp[4], tp[5], tp[6], tp[7]};
      *reinterpret_cast<uint4*>(&Ah[am * 72 + akq]) = s0;
      *reinterpret_cast<uint4*>(&Ah[am * 72 + akq + 8]) = s1;
    }
    {  // stage B (x) -> fp16
#pragma unroll
      for (int u = 0; u < 4; ++u) {
        const float4 x4 =
            *reinterpret_cast<const float4*>(&x[(size_t)(ko + bk) * 32768 + n0 + bn4 + u * 4]);
        uint2 p;
        p.x = pack2(x4.x, x4.y);
        p.y = pack2(x4.z, x4.w);
        *reinterpret_cast<uint2*>(&Bh[bk * 66 + bn4 + u * 4]) = p;
      }
    }
    __syncthreads();
#pragma unroll
    for (int kk = 0; kk < 64; kk += 32) {
      half8_t af[2], bf[2];
#pragma unroll
      for (int fm = 0; fm < 2; ++fm) {
        const int mrow = wm + fm * 16 + l15;
        af[fm] = *reinterpret_cast<const half8_t*>(&Ah[mrow * 72 + kk + kg * 8]);
      }
#pragma unroll
      for (int fn = 0; fn < 2; ++fn) {
        const int ncol = wn + fn * 16 + l15;
        half8_t bv;
#pragma unroll
        for (int e = 0; e < 8; ++e)
          bv[e] = __builtin_bit_cast(_Float16, Bh[(kk + kg * 8 + e) * 66 + ncol]);
        bf[fn] = bv;
      }
#pragma unroll
      for (int fm = 0; fm < 2; ++fm)
#pragma unroll
        for (int fn = 0; fn < 2; ++fn)
          acc[fm][fn] =
              __builtin_amdgcn_mfma_f32_16x16x32_f16(af[fm], bf[fn], acc[fm][fn], 0, 0, 0);
    }
  }

  const int b = blockIdx.x;
#pragma unroll
  for (int fm = 0; fm < 2; ++fm) {
    float sc[4], sh[4];
#pragma unroll
    for (int reg = 0; reg < 4; ++reg) {
      const int o = o0 + wm + fm * 16 + kg * 4 + reg;
      sc[reg] = bnq[o] / sqrtf(bnq[1536 + o] + EPS);
      sh[reg] = bnq[512 + o] - bnq[1024 + o] * sc[reg];
    }
#pragma unroll
    for (int fn = 0; fn < 2; ++fn) {
      const int h = wn + fn * 16 + l15;
#pragma unroll
      for (int reg = 0; reg < 4; ++reg) {
        const int o = o0 + wm + fm * 16 + kg * 4 + reg;
        qkv[((size_t)b * 512 + o) * 64 + h] = fmaf(acc[fm][fn][reg], sc[reg], sh[reg]);
      }
    }
  }
}

// ---------------------------------------------------------------------------
// Kernel 2: per (b,g) attention, fp16 MFMA.
//  qk = q^T k, M1 = q^T rel_q, M2 = k^T rel_k  (K=16, mfma_f32_16x16x16f16)
//  S[i][j] = scA*qk + scB*M1[i][i-j+63] + scC*M2[j][j-i+63] + sh
//  softmax -> P (fp16) and P'[i][t]=P[i][i+63-t] (scatter + zero complement)
//  sv = P v^T (K=64); sve = P' rel_v^T (K=128), mfma_f32_16x16x32_f16
// Arena 62464 B (2 blocks/CU). All staging writes contiguous 8/16B chunks.
// ---------------------------------------------------------------------------
#define M1S 130  // M1/M2 row stride (halves)
#define PS 72    // P / V row stride (halves)
#define PPS 136  // P' / RV row stride (halves)
#define SS 66    // S row stride (floats); col 64 = rowsum

__global__ __launch_bounds__(256) void k_attn(const float* __restrict__ qkv,
                                              const float* __restrict__ rel,
                                              const float* __restrict__ bns,
                                              const float* __restrict__ bno,
                                              float* __restrict__ out) {
  __shared__ __align__(16) char arena[62464];
  float* S_s = reinterpret_cast<float*>(arena);                    // 16896
  unsigned short* qT = reinterpret_cast<unsigned short*>(arena + 16896);  // [64 i][16 c]
  unsigned short* kT = reinterpret_cast<unsigned short*>(arena + 18944);  // [64 i][16 c]
  unsigned short* rq = reinterpret_cast<unsigned short*>(arena + 20992);  // [128 t][16 c]
  unsigned short* rk = reinterpret_cast<unsigned short*>(arena + 25088);  // [128 t][16 c]
  unsigned short* M1 = reinterpret_cast<unsigned short*>(arena + 29184);  // [64][130]
  unsigned short* M2 = reinterpret_cast<unsigned short*>(arena + 45824);  // [64][130]
  // phase 4-5 overlay (staging + M1/M2 dead):
  unsigned short* Vb = reinterpret_cast<unsigned short*>(arena + 16896);   // [32 c][72]
  unsigned short* RVb = reinterpret_cast<unsigned short*>(arena + 21504);  // [32 c][136]
  unsigned short* Pb = reinterpret_cast<unsigned short*>(arena + 30208);   // [64 i][72]
  unsigned short* Pp = reinterpret_cast<unsigned short*>(arena + 39424);   // [64 i][136]

  const int tid = threadIdx.x;
  const int lane = tid & 63;
  const int wid = tid >> 6;
  const int l15 = lane & 15, kg = lane >> 4;
  const int bg = blockIdx.x;
  const int b = bg >> 3, g = bg & 7;
  const float* src = qkv + ((size_t)b * 512 + (size_t)g * 64) * 64;

  const float scA = bns[g] / sqrtf(bns[72 + g] + EPS);
  const float scB = bns[8 + g] / sqrtf(bns[72 + 8 + g] + EPS);
  const float scC = bns[16 + g] / sqrtf(bns[72 + 16 + g] + EPS);
  const float shv = (bns[24 + g] - bns[48 + g] * scA) +
                    (bns[24 + 8 + g] - bns[48 + 8 + g] * scB) +
                    (bns[24 + 16 + g] - bns[48 + 16 + g] * scC);

  // ---- phase 1: stage qT,kT (row-contiguous writes) + rq,rk ----
  {
    const int i = tid >> 2, c0 = (tid & 3) * 4;  // 4 coalesced 64B segments/instr
    float qv[4], kv[4];
#pragma unroll
    for (int e = 0; e < 4; ++e) {
      qv[e] = src[(c0 + e) * 64 + i];
      kv[e] = src[(16 + c0 + e) * 64 + i];
    }
    uint2 qp, kp;
    qp.x = pack2(qv[0], qv[1]);
    qp.y = pack2(qv[2], qv[3]);
    kp.x = pack2(kv[0], kv[1]);
    kp.y = pack2(kv[2], kv[3]);
    *reinterpret_cast<uint2*>(&qT[i * 16 + c0]) = qp;
    *reinterpret_cast<uint2*>(&kT[i * 16 + c0]) = kp;
  }
  {
    const int t = tid >> 1, c0 = (tid & 1) * 8;  // 2 coalesced 128B segments/instr
    unsigned short vq[8], vk[8];
#pragma unroll
    for (int e = 0; e < 8; ++e) {
      vq[e] = (t < 127) ? f2hb(rel[(c0 + e) * 127 + t]) : (unsigned short)0;
      vk[e] = (t < 127) ? f2hb(rel[(16 + c0 + e) * 127 + t]) : (unsigned short)0;
    }
    uint4 wq, wk;
    wq.x = (unsigned int)vq[0] | ((unsigned int)vq[1] << 16);
    wq.y = (unsigned int)vq[2] | ((unsigned int)vq[3] << 16);
    wq.z = (unsigned int)vq[4] | ((unsigned int)vq[5] << 16);
    wq.w = (unsigned int)vq[6] | ((unsigned int)vq[7] << 16);
    wk.x = (unsigned int)vk[0] | ((unsigned int)vk[1] << 16);
    wk.y = (unsigned int)vk[2] | ((unsigned int)vk[3] << 16);
    wk.z = (unsigned int)vk[4] | ((unsigned int)vk[5] << 16);
    wk.w = (unsigned int)vk[6] | ((unsigned int)vk[7] << 16);
    *reinterpret_cast<uint4*>(&rq[t * 16 + c0]) = wq;
    *reinterpret_cast<uint4*>(&rk[t * 16 + c0]) = wk;
  }
  __syncthreads();

  // ---- phase 2: K=16 MFMAs: qk (regs), M1, M2 (LDS, fp16) ----
  floatx4 qkreg[4];
  {
    const half4_t aq = *reinterpret_cast<const half4_t*>(&qT[(wid * 16 + l15) * 16 + kg * 4]);
#pragma unroll
    for (int nt = 0; nt < 4; ++nt) {
      const half4_t bq = *reinterpret_cast<const half4_t*>(&kT[(nt * 16 + l15) * 16 + kg * 4]);
      const floatx4 z = {};
      qkreg[nt] = __builtin_amdgcn_mfma_f32_16x16x16f16(aq, bq, z, 0, 0, 0);
    }
#pragma unroll
    for (int nt = 0; nt < 8; ++nt) {
      const half4_t br = *reinterpret_cast<const half4_t*>(&rq[(nt * 16 + l15) * 16 + kg * 4]);
      const floatx4 z = {};
      const floatx4 cr = __builtin_amdgcn_mfma_f32_16x16x16f16(aq, br, z, 0, 0, 0);
#pragma unroll
      for (int r = 0; r < 4; ++r)
        M1[(wid * 16 + kg * 4 + r) * M1S + nt * 16 + l15] = f2hb(cr[r]);
    }
    const half4_t ak = *reinterpret_cast<const half4_t*>(&kT[(wid * 16 + l15) * 16 + kg * 4]);
#pragma unroll
    for (int nt = 0; nt < 8; ++nt) {
      const half4_t br = *reinterpret_cast<const half4_t*>(&rk[(nt * 16 + l15) * 16 + kg * 4]);
      const floatx4 z = {};
      const floatx4 cr = __builtin_amdgcn_mfma_f32_16x16x16f16(ak, br, z, 0, 0, 0);
#pragma unroll
      for (int r = 0; r < 4; ++r)
        M2[(wid * 16 + kg * 4 + r) * M1S + nt * 16 + l15] = f2hb(cr[r]);
    }
  }
  __syncthreads();

  // ---- phase 3: assemble S ----
#pragma unroll
  for (int nt = 0; nt < 4; ++nt) {
    const int j = nt * 16 + l15;
#pragma unroll
    for (int r = 0; r < 4; ++r) {
      const int i = wid * 16 + kg * 4 + r;
      const int d = i - j + 63;  // 0..126
      const float qr = hb2f(M1[i * M1S + d]);
      const float kr = hb2f(M2[j * M1S + 126 - d]);
      S_s[i * SS + j] = fmaf(scA, qkreg[nt][r], fmaf(scB, qr, fmaf(scC, kr, shv)));
    }
  }
  __syncthreads();

  // ---- phase 4: softmax -> Pb + Pp (scatter + zero complement); stage V, RV ----
  {
    const int i = tid >> 2, sub = tid & 3;
    const float* row = S_s + i * SS + sub * 16;
    float ev[16];
#pragma unroll
    for (int p = 0; p < 8; ++p) {
      const float2 v2 = *reinterpret_cast<const float2*>(row + p * 2);
      ev[p * 2] = v2.x;
      ev[p * 2 + 1] = v2.y;
    }
    float m = ev[0];
#pragma unroll
    for (int jj = 1; jj < 16; ++jj) m = fmaxf(m, ev[jj]);
    m = fmaxf(m, __shfl_xor(m, 1));
    m = fmaxf(m, __shfl_xor(m, 2));
    float sum = 0.f;
#pragma unroll
    for (int jj = 0; jj < 16; ++jj) {
      ev[jj] = __expf(ev[jj] - m);
      sum += ev[jj];
    }
    sum += __shfl_xor(sum, 1);
    sum += __shfl_xor(sum, 2);
    if (sub == 0) S_s[i * SS + 64] = sum;  // rowsum slot
    unsigned int* pw = reinterpret_cast<unsigned int*>(Pb) + i * (PS / 2) + sub * 8;
#pragma unroll
    for (int p = 0; p < 8; ++p) {  // xor-staggered issue order, true columns
      const int pp = p ^ (i & 7);
      pw[pp] = pack2(ev[2 * pp], ev[2 * pp + 1]);
    }
    const int base = i * PPS;
#pragma unroll
    for (int jj = 0; jj < 16; ++jj) {
      const int j = sub * 16 + jj;
      Pp[base + i + 63 - j] = f2hb(ev[jj]);
    }
#pragma unroll
    for (int jj = 0; jj < 16; ++jj) {  // zero complement of [i, i+63]
      const int z = sub * 16 + jj;
      const int t0 = (z < i) ? z : z + 64;
      Pp[base + t0] = 0;
    }
  }
  {
    const int cv = tid >> 3, t8 = tid & 7;
    const float4 a = *reinterpret_cast<const float4*>(&src[(32 + cv) * 64 + t8 * 8]);
    const float4 b2 = *reinterpret_cast<const float4*>(&src[(32 + cv) * 64 + t8 * 8 + 4]);
    uint4 wv;
    wv.x = pack2(a.x, a.y);
    wv.y = pack2(a.z, a.w);
    wv.z = pack2(b2.x, b2.y);
    wv.w = pack2(b2.z, b2.w);
    *reinterpret_cast<uint4*>(&Vb[cv * PS + t8 * 8]) = wv;
    const int t0 = t8 * 16;
    unsigned short tv[16];
#pragma unroll
    for (int e = 0; e < 16; ++e) {
      const int t = t0 + e;
      tv[e] = (t < 127) ? f2hb(rel[(32 + cv) * 127 + t]) : (unsigned short)0;
    }
    uint4 w0, w1;
    w0.x = (unsigned int)tv[0] | ((unsigned int)tv[1] << 16);
    w0.y = (unsigned int)tv[2] | ((unsigned int)tv[3] << 16);
    w0.z = (unsigned int)tv[4] | ((unsigned int)tv[5] << 16);
    w0.w = (unsigned int)tv[6] | ((unsigned int)tv[7] << 16);
    w1.x = (unsigned int)tv[8] | ((unsigned int)tv[9] << 16);
    w1.y = (unsigned int)tv[10] | ((unsigned int)tv[11] << 16);
    w1.z = (unsigned int)tv[12] | ((unsigned int)tv[13] << 16);
    w1.w = (unsigned int)tv[14] | ((unsigned int)tv[15] << 16);
    *reinterpret_cast<uint4*>(&RVb[cv * PPS + t0]) = w0;
    *reinterpret_cast<uint4*>(&RVb[cv * PPS + t0 + 8]) = w1;
  }
  __syncthreads();

  // ---- phase 5: sv / sve MFMAs (fp16 K=32) + BN epilogue ----
  floatx4 sva[2] = {}, svea[2] = {};
#pragma unroll
  for (int kk = 0; kk < 2; ++kk) {
    const half8_t pa =
        *reinterpret_cast<const half8_t*>(&Pb[(wid * 16 + l15) * PS + kk * 32 + kg * 8]);
#pragma unroll
    for (int nt = 0; nt < 2; ++nt) {
      const half8_t vb =
          *reinterpret_cast<const half8_t*>(&Vb[(nt * 16 + l15) * PS + kk * 32 + kg * 8]);
      sva[nt] = __builtin_amdgcn_mfma_f32_16x16x32_f16(pa, vb, sva[nt], 0, 0, 0);
    }
  }
#pragma unroll
  for (int kk = 0; kk < 4; ++kk) {
    const half8_t pp =
        *reinterpret_cast<const half8_t*>(&Pp[(wid * 16 + l15) * PPS + kk * 32 + kg * 8]);
#pragma unroll
    for (int nt = 0; nt < 2; ++nt) {
      const half8_t rb =
          *reinterpret_cast<const half8_t*>(&RVb[(nt * 16 + l15) * PPS + kk * 32 + kg * 8]);
      svea[nt] = __builtin_amdgcn_mfma_f32_16x16x32_f16(pp, rb, svea[nt], 0, 0, 0);
    }
  }
#pragma unroll
  for (int nt = 0; nt < 2; ++nt) {
    const int c = nt * 16 + l15;
    const int ch = ((g << 5) + c) * 2;
    const float sc0 = bno[ch] / sqrtf(bno[1536 + ch] + EPS);
    const float sh0 = bno[512 + ch] - bno[1024 + ch] * sc0;
    const float sc1 = bno[ch + 1] / sqrtf(bno[1536 + ch + 1] + EPS);
    const float sh1 = bno[512 + ch + 1] - bno[1024 + ch + 1] * sc1;
#pragma unroll
    for (int r = 0; r < 4; ++r) {
      const int i = wid * 16 + kg * 4 + r;
      const float inv = 1.0f / S_s[i * SS + 64];
      const float val = fmaf(sc0, sva[nt][r] * inv, sh0) + fmaf(sc1, svea[nt][r] * inv, sh1);
      S_s[c * SS + i] = val;  // out-tile [c][i]
    }
  }
  __syncthreads();
  {
    const size_t outbase = (size_t)b * 64;
#pragma unroll
    for (int r = 0; r < 8; ++r) {
      const int idx = tid + r * 256;
      const int cc = idx >> 6, ii = idx & 63;
      out[(size_t)((g << 5) + cc) * 32768 + outbase + ii] = S_s[cc * SS + ii];
    }
  }
}

extern "C" void kernel_launch(void* const* d_in, const int* in_sizes, int n_in,
                              void* d_out, int out_size, void* d_ws, size_t ws_size,
                              hipStream_t stream) {
  const float* x = (const float*)d_in[0];         // (1,256,16,32,64)
  const float* qkv_w = (const float*)d_in[1];     // (512,256)
  const float* relative = (const float*)d_in[2];  // (64,127)
  const float* bn_qkv = (const float*)d_in[3];    // (4,512)
  const float* bn_sim = (const float*)d_in[4];    // (4,24)
  const float* bn_out = (const float*)d_in[5];    // (4,512)
  float* out = (float*)d_out;                     // (256, 512, 64) as [op][b][h]
  float* qkv = (float*)d_ws;                      // 64 MB scratch

  k_qkv_gemm<<<dim3(512, 8), 256, 0, stream>>>(x, qkv_w, bn_qkv, qkv);
  k_attn<<<4096, 256, 0, stream>>>(qkv, relative, bn_sim, bn_out, out);
}